// Round 8
// baseline (143.469 us; speedup 1.0000x reference)
//
#include <hip/hip_runtime.h>
#include <math.h>

#define NN 4096
#define DD 256
#define EPSV 1e-4f
#define STABV 1e-8f
#define AVAL (1.0f / 4096.0f)
#define BVAL (1.0f / 4096.0f)
#define MAX_IT 2000
#define NB 512           // coop grid: 512 blocks x 512 thr = 2 blocks/CU guaranteed resident
#define RPB 8            // rows per block in coop phases

typedef __attribute__((ext_vector_type(4))) float f32x4;
typedef __attribute__((ext_vector_type(8))) short bf16x8;

__device__ inline unsigned short f2bf(float f) {   // RNE f32->bf16
    unsigned u = __float_as_uint(f);
    return (unsigned short)((u + 0x7fffu + ((u >> 16) & 1u)) >> 16);
}
__device__ inline float bflo(unsigned w) { return __uint_as_float(w << 16); }
__device__ inline float bfhi(unsigned w) { return __uint_as_float(w & 0xffff0000u); }

// ---- MALL-coherent (cache-bypassing) access for cross-block data inside coop kernel ----
__device__ __forceinline__ void st_sys_f32(float* p, float v) {
    asm volatile("global_store_dword %0, %1, off sc0 sc1" :: "v"(p), "v"(v) : "memory");
}
__device__ __forceinline__ float ld_sys_f32(const float* p) {
    float r;
    asm volatile("global_load_dword %0, %1, off sc0 sc1\n\ts_waitcnt vmcnt(0)"
                 : "=v"(r) : "v"(p) : "memory");
    return r;
}
__device__ __forceinline__ float4 ld_sys_f32x4(const float* p) {
    float4 r;
    asm volatile("global_load_dwordx4 %0, %1, off sc0 sc1\n\ts_waitcnt vmcnt(0)"
                 : "=v"(r) : "v"(p) : "memory");
    return r;
}

// ---------------- conv f32->bf16 + row norms + zero control state / ksum ----------------
__global__ __launch_bounds__(256) void sk_conv_kernel(const float* __restrict__ x,
                                                      const float* __restrict__ y,
                                                      unsigned short* __restrict__ xb,
                                                      unsigned short* __restrict__ yb,
                                                      float* __restrict__ x2,
                                                      float* __restrict__ y2,
                                                      float* __restrict__ sumC,
                                                      float* __restrict__ ksumK,
                                                      unsigned* __restrict__ flags,
                                                      unsigned* __restrict__ bar) {
    int w = blockIdx.x * 4 + (threadIdx.x >> 6);   // row id 0..8191
    int lane = threadIdx.x & 63;
    const float* src = (w < NN) ? (x + (size_t)w * DD) : (y + (size_t)(w - NN) * DD);
    unsigned short* dst = (w < NN) ? (xb + (size_t)w * DD) : (yb + (size_t)(w - NN) * DD);
    float4 v = *(const float4*)(src + lane * 4);
    float s = v.x * v.x + v.y * v.y + v.z * v.z + v.w * v.w;
    ushort4 p;
    p.x = f2bf(v.x); p.y = f2bf(v.y); p.z = f2bf(v.z); p.w = f2bf(v.w);
    *(ushort4*)(dst + lane * 4) = p;
#pragma unroll
    for (int off = 32; off > 0; off >>= 1) s += __shfl_down(s, off, 64);
    if (lane == 0) {
        if (w < NN) x2[w] = s; else y2[w - NN] = s;
    }
    if (blockIdx.x == 0) {
        int t = threadIdx.x;
        if (t == 0) { sumC[0] = 0.0f; flags[0] = 0u; flags[1] = 0u; }
        for (int i = t; i < 384; i += 256) bar[i] = 0u;
    } else if (blockIdx.x == 1) {
        int t = threadIdx.x;
        for (int i = t; i < NN; i += 256) ksumK[i] = 0.0f;
    }
}

// ---------------- MFMA GEMM: Cb = bf16( sqrt(max(x2_i + y2_j - 2 x.y, 0)) ), sum(C) ----------------
// Epilogue stages 32-row slabs in LDS, then stores full rows with dwordx4 (vs scalar b16 stores).
__global__ __launch_bounds__(256) void sk_gemm_kernel(const unsigned short* __restrict__ xb,
                                                      const unsigned short* __restrict__ yb,
                                                      const float* __restrict__ x2,
                                                      const float* __restrict__ y2,
                                                      unsigned short* __restrict__ Cb,
                                                      float* __restrict__ sumC) {
    __shared__ unsigned short st[32][144];   // 144 = 128 + 16 pad: 4-row bank offsets {0,8,16,24}, 16B-aligned rows
    __shared__ float red[256];
    const int tid = threadIdx.x;
    const int wid = tid >> 6, lane = tid & 63;
    const int wy = wid >> 1, wx = wid & 1;
    const int rb0 = blockIdx.y * 128, cb0 = blockIdx.x * 128;
    const int lr = lane & 15;
    const int lk = (lane >> 4) * 8;
    const int qr = (lane >> 4) * 4;          // row quad base within 16x16 tile

    f32x4 acc[4][4];
    const f32x4 z4 = {0.0f, 0.0f, 0.0f, 0.0f};
#pragma unroll
    for (int a = 0; a < 4; ++a)
#pragma unroll
        for (int b = 0; b < 4; ++b) acc[a][b] = z4;

#pragma unroll
    for (int k0 = 0; k0 < DD; k0 += 32) {
        bf16x8 af[4], bfr[4];
#pragma unroll
        for (int t = 0; t < 4; ++t)
            af[t] = *(const bf16x8*)(xb + (size_t)(rb0 + wy * 64 + t * 16 + lr) * DD + k0 + lk);
#pragma unroll
        for (int t = 0; t < 4; ++t)
            bfr[t] = *(const bf16x8*)(yb + (size_t)(cb0 + wx * 64 + t * 16 + lr) * DD + k0 + lk);
#pragma unroll
        for (int ty = 0; ty < 4; ++ty)
#pragma unroll
            for (int tx = 0; tx < 4; ++tx)
                acc[ty][tx] = __builtin_amdgcn_mfma_f32_16x16x32_bf16(af[ty], bfr[tx], acc[ty][tx], 0, 0, 0);
    }

    // epilogue: per 32-row slab s: matching waves drop bf16 into LDS, all threads store vectorized
    float lsum = 0.0f;
#pragma unroll
    for (int s = 0; s < 4; ++s) {
        if (wy == (s >> 1)) {
#pragma unroll
            for (int h = 0; h < 2; ++h) {
                const int ty = (s & 1) * 2 + h;
                float x2r[4];
#pragma unroll
                for (int r = 0; r < 4; ++r)
                    x2r[r] = x2[rb0 + wy * 64 + ty * 16 + qr + r];
#pragma unroll
                for (int tx = 0; tx < 4; ++tx) {
                    const int lcol = wx * 64 + tx * 16 + lr;
                    const float y2c = y2[cb0 + lcol];
#pragma unroll
                    for (int r = 0; r < 4; ++r) {
                        float sq = x2r[r] + y2c - 2.0f * acc[ty][tx][r];
                        float c = sqrtf(fmaxf(sq, 0.0f));
                        lsum += c;
                        st[h * 16 + qr + r][lcol] = f2bf(c);
                    }
                }
            }
        }
        __syncthreads();
#pragma unroll
        for (int i = 0; i < 2; ++i) {
            const int un = i * 256 + tid;           // unit of 8 ushorts (16 B)
            const int srow = un >> 4, cu = (un & 15) * 8;
            ulonglong2 val = *(const ulonglong2*)&st[srow][cu];
            *(ulonglong2*)(Cb + (size_t)(rb0 + s * 32 + srow) * NN + cb0 + cu) = val;
        }
        __syncthreads();
    }

    red[tid] = lsum;
    __syncthreads();
    for (int off = 128; off > 0; off >>= 1) {
        if (tid < off) red[tid] += red[tid + off];
        __syncthreads();
    }
    if (tid == 0) atomicAdd(sumC, red[0]);
}

// ---------------- ksum: ksumK[j] = sum_i exp(C_ij * nrs); uint4 loads, 512x128 blocks ----------------
__global__ __launch_bounds__(256) void sk_ksum_kernel(const unsigned short* __restrict__ Cb,
                                                      const float* __restrict__ sumC,
                                                      float* __restrict__ ksumK) {
    __shared__ float ks[4][516];
    const int t = threadIdx.x;
    const int g = t >> 6, ln = t & 63;
    const int c0 = blockIdx.x * 512 + ln * 8;
    const int r0 = blockIdx.y * 128 + g;
    const float mean = sumC[0] * (1.0f / ((float)NN * (float)NN));
    const float nrs = -1.0f / (mean * EPSV);
    float a[8] = {0, 0, 0, 0, 0, 0, 0, 0};
#pragma unroll
    for (int k = 0; k < 32; ++k) {
        int r = r0 + k * 4;
        uint4 cw = *(const uint4*)(Cb + (size_t)r * NN + c0);
        a[0] += __expf(bflo(cw.x) * nrs);
        a[1] += __expf(bfhi(cw.x) * nrs);
        a[2] += __expf(bflo(cw.y) * nrs);
        a[3] += __expf(bfhi(cw.y) * nrs);
        a[4] += __expf(bflo(cw.z) * nrs);
        a[5] += __expf(bfhi(cw.z) * nrs);
        a[6] += __expf(bflo(cw.w) * nrs);
        a[7] += __expf(bfhi(cw.w) * nrs);
    }
#pragma unroll
    for (int q = 0; q < 8; ++q) ks[g][ln * 8 + q] = a[q];
    __syncthreads();
    for (int c = t; c < 512; c += 256) {
        float s = ks[0][c] + ks[1][c] + ks[2][c] + ks[3][c];
        atomicAdd(&ksumK[blockIdx.x * 512 + c], s);
    }
}

// ---- fence-free hierarchical grid barrier (cross-block data uses sc0sc1 ops) ----
__device__ __forceinline__ void gridbar(unsigned* bar, unsigned target) {
    asm volatile("s_waitcnt vmcnt(0)" ::: "memory");
    __syncthreads();
    if (threadIdx.x == 0) {
        const int sg = blockIdx.x & 7;
        const unsigned bps = NB >> 3;
        unsigned p = __hip_atomic_fetch_add(&bar[sg * 32], 1u, __ATOMIC_RELAXED, __HIP_MEMORY_SCOPE_AGENT);
        if (p == target * bps - 1u) {
            unsigned q = __hip_atomic_fetch_add(&bar[256], 1u, __ATOMIC_RELAXED, __HIP_MEMORY_SCOPE_AGENT);
            if (q == target * 8u - 1u)
                __hip_atomic_store(&bar[288], target, __ATOMIC_RELAXED, __HIP_MEMORY_SCOPE_AGENT);
        }
        while (__hip_atomic_load(&bar[288], __ATOMIC_RELAXED, __HIP_MEMORY_SCOPE_AGENT) < target)
            __builtin_amdgcn_s_sleep(1);
    }
    __syncthreads();
}

// ---------------- Sinkhorn loop: it1 via ksum; Phase A fused with cost; bitwise fixed-point exit ----------------
__global__ __launch_bounds__(512, 4) void sk_coop_kernel(const unsigned short* __restrict__ Cb,
                                                         float* __restrict__ u,
                                                         float* __restrict__ v,
                                                         const float* __restrict__ ksumK,
                                                         const float* __restrict__ sumC,
                                                         unsigned* __restrict__ flags,
                                                         float* __restrict__ costpart,
                                                         unsigned* __restrict__ bar,
                                                         float* __restrict__ out) {
    __shared__ float vec[NN];          // 16 KB: v-cache (Phase A) / u-cache (fallback B)
    __shared__ float pu[RPB], pv[RPB];
    __shared__ float csum[RPB];
    __shared__ float ws8[8][8];
    const int t = threadIdx.x;         // 0..511
    const int bid = blockIdx.x;
    const int r8 = t >> 6;             // wave id 0..7 == row within block's chunk
    const int lane = t & 63;
    const float mean = sumC[0] * (1.0f / ((float)NN * (float)NN));
    const float nrs = -1.0f / (mean * EPSV);   // K = exp(C_raw * nrs)
    const float invMean = 1.0f / mean;
    unsigned bars = 0;

    // ---- it = 1: u1 = a/stab (uniform since v0 == 0); v1 = b/(u1*colsum(K) + stab) ----
    if (t < RPB) {
        float u1 = AVAL / (0.0f + STABV);
        pu[t] = u1;
        st_sys_f32(&u[bid * RPB + t], u1);
        float ks = ksumK[bid * RPB + t];       // prior dispatch: plain load is coherent
        float v1 = BVAL / (u1 * ks + STABV);
        pv[t] = v1;
        st_sys_f32(&v[bid * RPB + t], v1);
    }
    gridbar(bar, ++bars);

    for (int it = 2; it <= MAX_IT; ++it) {
        // ---- Phase A: u = a / (K v + stab), fused cost partial (rows of Cb) ----
        {
            float4 a = ld_sys_f32x4(v + t * 8);
            float4 b = ld_sys_f32x4(v + t * 8 + 4);
            *(float4*)&vec[t * 8] = a;
            *(float4*)&vec[t * 8 + 4] = b;
        }
        __syncthreads();
        const int i = bid * RPB + r8;
        const unsigned short* Crow = Cb + (size_t)i * NN;
        float acc = 0.0f, ts = 0.0f;
#pragma unroll
        for (int k = 0; k < 8; ++k) {
            int c0 = lane * 8 + k * 512;
            uint4 cw = *(const uint4*)(Crow + c0);
            float4 v0 = *(const float4*)&vec[c0];
            float4 v1 = *(const float4*)&vec[c0 + 4];
            float c, t1;
            c = bflo(cw.x); t1 = __expf(c * nrs) * v0.x; acc += t1; ts += t1 * c;
            c = bfhi(cw.x); t1 = __expf(c * nrs) * v0.y; acc += t1; ts += t1 * c;
            c = bflo(cw.y); t1 = __expf(c * nrs) * v0.z; acc += t1; ts += t1 * c;
            c = bfhi(cw.y); t1 = __expf(c * nrs) * v0.w; acc += t1; ts += t1 * c;
            c = bflo(cw.z); t1 = __expf(c * nrs) * v1.x; acc += t1; ts += t1 * c;
            c = bfhi(cw.z); t1 = __expf(c * nrs) * v1.y; acc += t1; ts += t1 * c;
            c = bflo(cw.w); t1 = __expf(c * nrs) * v1.z; acc += t1; ts += t1 * c;
            c = bfhi(cw.w); t1 = __expf(c * nrs) * v1.w; acc += t1; ts += t1 * c;
        }
#pragma unroll
        for (int off = 32; off > 0; off >>= 1) {
            acc += __shfl_down(acc, off, 64);
            ts += __shfl_down(ts, off, 64);
        }
        if (lane == 0) {
            float un = AVAL / (acc + STABV);
            if (un != pu[r8])
                __hip_atomic_store(&flags[it & 1], 1u, __ATOMIC_RELAXED, __HIP_MEMORY_SCOPE_AGENT);
            pu[r8] = un;
            st_sys_f32(&u[i], un);
            csum[r8] = un * ts * invMean;     // cost_i = u_i * sum_j K c v / mean
        }
        __syncthreads();
        if (t == 0) {
            float cp = 0.0f;
#pragma unroll
            for (int q = 0; q < RPB; ++q) cp += csum[q];
            st_sys_f32(&costpart[bid], cp);
        }
        if (bid == 0 && t == 0)
            __hip_atomic_store(&flags[(it + 1) & 1], 0u, __ATOMIC_RELAXED, __HIP_MEMORY_SCOPE_AGENT);
        gridbar(bar, ++bars);

        unsigned fl = __hip_atomic_load(&flags[it & 1], __ATOMIC_RELAXED, __HIP_MEMORY_SCOPE_AGENT);
        if (fl == 0u) break;   // u bitwise fixed -> deterministic recompute of v is fixed too

        // ---- Phase B (generic fallback): v = b/(K^T u + stab), col-stripe walk of Cb ----
        {
            float4 a = ld_sys_f32x4(u + t * 8);
            float4 b = ld_sys_f32x4(u + t * 8 + 4);
            *(float4*)&vec[t * 8] = a;
            *(float4*)&vec[t * 8 + 4] = b;
        }
        __syncthreads();
        const int j0 = bid * RPB;
        float a8[8] = {0, 0, 0, 0, 0, 0, 0, 0};
#pragma unroll
        for (int k = 0; k < 8; ++k) {
            int r = t + k * 512;
            uint4 cw = *(const uint4*)(Cb + (size_t)r * NN + j0);
            float ui = vec[r];
            a8[0] += __expf(bflo(cw.x) * nrs) * ui;
            a8[1] += __expf(bfhi(cw.x) * nrs) * ui;
            a8[2] += __expf(bflo(cw.y) * nrs) * ui;
            a8[3] += __expf(bfhi(cw.y) * nrs) * ui;
            a8[4] += __expf(bflo(cw.z) * nrs) * ui;
            a8[5] += __expf(bfhi(cw.z) * nrs) * ui;
            a8[6] += __expf(bflo(cw.w) * nrs) * ui;
            a8[7] += __expf(bfhi(cw.w) * nrs) * ui;
        }
#pragma unroll
        for (int off = 32; off > 0; off >>= 1)
#pragma unroll
            for (int q = 0; q < 8; ++q) a8[q] += __shfl_down(a8[q], off, 64);
        if (lane == 0)
#pragma unroll
            for (int q = 0; q < 8; ++q) ws8[r8][q] = a8[q];
        __syncthreads();
        if (t < RPB) {
            float s = 0.0f;
#pragma unroll
            for (int g = 0; g < 8; ++g) s += ws8[g][t];
            float vn = BVAL / (s + STABV);
            pv[t] = vn;
            st_sys_f32(&v[j0 + t], vn);
        }
        gridbar(bar, ++bars);
    }

    // ---- outputs: [cost, u(4096), v(4096)] ----
    if (t < RPB) {
        out[1 + bid * RPB + t] = pu[t];
        out[1 + NN + bid * RPB + t] = pv[t];
    }
    if (bid == 0) {
        __shared__ float cred[512];
        cred[t] = ld_sys_f32(&costpart[t]);
        __syncthreads();
        for (int off = 256; off > 0; off >>= 1) {
            if (t < off) cred[t] += cred[t + off];
            __syncthreads();
        }
        if (t == 0) out[0] = cred[0];
    }
}

extern "C" void kernel_launch(void* const* d_in, const int* in_sizes, int n_in,
                              void* d_out, int out_size, void* d_ws, size_t ws_size,
                              hipStream_t stream) {
    const float* x = (const float*)d_in[0];
    const float* y = (const float*)d_in[1];
    float* out = (float*)d_out;

    // ws layout
    unsigned short* Cb = (unsigned short*)d_ws;          // N*N bf16 = 32 MB
    unsigned short* xb = Cb + (size_t)NN * NN;           // N*D bf16
    unsigned short* yb = xb + (size_t)NN * DD;           // N*D bf16
    float* fbase = (float*)(yb + (size_t)NN * DD);
    float* x2    = fbase;                                // N
    float* y2    = x2 + NN;                              // N
    float* u     = y2 + NN;                              // N
    float* v     = u + NN;                               // N
    float* ksumK = v + NN;                               // N (colsums of K)
    float* costpart = ksumK + NN;                        // 512
    float* sumC  = costpart + 512;                       // 1
    unsigned* flags = (unsigned*)(sumC + 1);             // 2
    unsigned* bar   = flags + 2;                         // 384

    size_t need = ((size_t)NN * NN + 2 * (size_t)NN * DD) * 2
                + (5 * NN + 520) * sizeof(float) + 400 * sizeof(unsigned);
    if (ws_size < need) return;

    sk_conv_kernel<<<dim3(2 * NN / 4), dim3(256), 0, stream>>>(x, y, xb, yb, x2, y2, sumC, ksumK, flags, bar);
    sk_gemm_kernel<<<dim3(NN / 128, NN / 128), dim3(256), 0, stream>>>(xb, yb, x2, y2, Cb, sumC);
    sk_ksum_kernel<<<dim3(NN / 512, NN / 128), dim3(256), 0, stream>>>(Cb, sumC, ksumK);
    sk_coop_kernel<<<dim3(NB), dim3(512), 0, stream>>>(Cb, u, v, ksumK, sumC, flags, costpart, bar, out);
}

// Round 9
// 118.268 us; speedup vs baseline: 1.2131x; 1.2131x over previous
//
#include <hip/hip_runtime.h>
#include <math.h>

#define NN 4096
#define DD 256
#define EPSV 1e-4f
#define STABV 1e-8f
#define AVAL (1.0f / 4096.0f)
#define BVAL (1.0f / 4096.0f)
#define MAX_IT 2000
#define NB 512           // coop grid: 512 blocks x 512 thr = 2 blocks/CU guaranteed resident
#define RPB 8            // rows per block in coop phases

typedef __attribute__((ext_vector_type(4))) float f32x4;
typedef __attribute__((ext_vector_type(8))) short bf16x8;

__device__ inline unsigned short f2bf(float f) {   // RNE f32->bf16
    unsigned u = __float_as_uint(f);
    return (unsigned short)((u + 0x7fffu + ((u >> 16) & 1u)) >> 16);
}
__device__ inline float bflo(unsigned w) { return __uint_as_float(w << 16); }
__device__ inline float bfhi(unsigned w) { return __uint_as_float(w & 0xffff0000u); }

// ---- MALL-coherent (cache-bypassing) access for cross-block data inside coop kernel ----
__device__ __forceinline__ void st_sys_f32(float* p, float v) {
    asm volatile("global_store_dword %0, %1, off sc0 sc1" :: "v"(p), "v"(v) : "memory");
}
__device__ __forceinline__ float ld_sys_f32(const float* p) {
    float r;
    asm volatile("global_load_dword %0, %1, off sc0 sc1\n\ts_waitcnt vmcnt(0)"
                 : "=v"(r) : "v"(p) : "memory");
    return r;
}
__device__ __forceinline__ float4 ld_sys_f32x4(const float* p) {
    float4 r;
    asm volatile("global_load_dwordx4 %0, %1, off sc0 sc1\n\ts_waitcnt vmcnt(0)"
                 : "=v"(r) : "v"(p) : "memory");
    return r;
}

// ---------------- conv f32->bf16 + row norms + zero control state / ksum ----------------
__global__ __launch_bounds__(256) void sk_conv_kernel(const float* __restrict__ x,
                                                      const float* __restrict__ y,
                                                      unsigned short* __restrict__ xb,
                                                      unsigned short* __restrict__ yb,
                                                      float* __restrict__ x2,
                                                      float* __restrict__ y2,
                                                      float* __restrict__ sumC,
                                                      float* __restrict__ ksumK,
                                                      unsigned* __restrict__ flags,
                                                      unsigned* __restrict__ bar) {
    int w = blockIdx.x * 4 + (threadIdx.x >> 6);   // row id 0..8191
    int lane = threadIdx.x & 63;
    const float* src = (w < NN) ? (x + (size_t)w * DD) : (y + (size_t)(w - NN) * DD);
    unsigned short* dst = (w < NN) ? (xb + (size_t)w * DD) : (yb + (size_t)(w - NN) * DD);
    float4 v = *(const float4*)(src + lane * 4);
    float s = v.x * v.x + v.y * v.y + v.z * v.z + v.w * v.w;
    ushort4 p;
    p.x = f2bf(v.x); p.y = f2bf(v.y); p.z = f2bf(v.z); p.w = f2bf(v.w);
    *(ushort4*)(dst + lane * 4) = p;
#pragma unroll
    for (int off = 32; off > 0; off >>= 1) s += __shfl_down(s, off, 64);
    if (lane == 0) {
        if (w < NN) x2[w] = s; else y2[w - NN] = s;
    }
    if (blockIdx.x == 0) {
        int t = threadIdx.x;
        if (t == 0) { sumC[0] = 0.0f; flags[0] = 0u; flags[1] = 0u; }
        for (int i = t; i < 384; i += 256) bar[i] = 0u;
    } else if (blockIdx.x == 1) {
        int t = threadIdx.x;
        for (int i = t; i < NN; i += 256) ksumK[i] = 0.0f;
    }
}

// ---------------- MFMA GEMM (m97-style LDS staging): Cb = bf16(dist), sum(C) ----------------
// 128x128 tile, BK=64 (4 steps). A/B staged via global_load_lds width=16; frags via ds_read_b128.
__global__ __launch_bounds__(256) void sk_gemm_kernel(const unsigned short* __restrict__ xb,
                                                      const unsigned short* __restrict__ yb,
                                                      const float* __restrict__ x2,
                                                      const float* __restrict__ y2,
                                                      unsigned short* __restrict__ Cb,
                                                      float* __restrict__ sumC) {
    __shared__ __attribute__((aligned(128))) char AsB[16384];  // A tile 128 rows x 64 k (bf16), row stride 128 B
    __shared__ __attribute__((aligned(128))) char BsB[16384];  // B tile
    __shared__ float red[256];
    const int tid = threadIdx.x;
    const int wid = tid >> 6, lane = tid & 63;
    const int wy = wid >> 1, wx = wid & 1;
    const int rb0 = blockIdx.y * 128, cb0 = blockIdx.x * 128;
    const int lr = lane & 15;            // row/col within 16x16 mfma tile
    const int lq = lane >> 4;            // quad 0..3 (k-chunk of 8 elements)
    const int srow8 = tid >> 3;          // staging: row-within-chunk 0..31
    const int scolb = (tid & 7) * 16;    // staging: byte col 0..112

    f32x4 acc[4][4];
    const f32x4 z4 = {0.0f, 0.0f, 0.0f, 0.0f};
#pragma unroll
    for (int a = 0; a < 4; ++a)
#pragma unroll
        for (int b = 0; b < 4; ++b) acc[a][b] = z4;

    for (int s = 0; s < 4; ++s) {
        const int k0 = s * 64;           // element k offset of this staged step
        if (s) __syncthreads();          // prior step's ds_reads done before overwrite
#pragma unroll
        for (int c = 0; c < 4; ++c) {    // chunk c = rows [c*32, c*32+32)
            const char* ga = (const char*)xb + ((size_t)(rb0 + c * 32 + srow8) * DD + k0) * 2 + scolb;
            __builtin_amdgcn_global_load_lds(
                (const __attribute__((address_space(1))) void*)ga,
                (__attribute__((address_space(3))) void*)(AsB + c * 4096 + wid * 1024), 16, 0, 0);
        }
#pragma unroll
        for (int c = 0; c < 4; ++c) {
            const char* gb = (const char*)yb + ((size_t)(cb0 + c * 32 + srow8) * DD + k0) * 2 + scolb;
            __builtin_amdgcn_global_load_lds(
                (const __attribute__((address_space(1))) void*)gb,
                (__attribute__((address_space(3))) void*)(BsB + c * 4096 + wid * 1024), 16, 0, 0);
        }
        asm volatile("s_waitcnt vmcnt(0)" ::: "memory");
        __syncthreads();                 // all waves' staging visible
#pragma unroll
        for (int m = 0; m < 2; ++m) {    // two K=32 MFMA sub-steps per staged BK=64
            bf16x8 af[4], bfr[4];
#pragma unroll
            for (int t = 0; t < 4; ++t)
                af[t] = *(const bf16x8*)(AsB + (wy * 64 + t * 16 + lr) * 128 + m * 64 + lq * 16);
#pragma unroll
            for (int t = 0; t < 4; ++t)
                bfr[t] = *(const bf16x8*)(BsB + (wx * 64 + t * 16 + lr) * 128 + m * 64 + lq * 16);
#pragma unroll
            for (int ty = 0; ty < 4; ++ty)
#pragma unroll
                for (int tx = 0; tx < 4; ++tx)
                    acc[ty][tx] = __builtin_amdgcn_mfma_f32_16x16x32_bf16(af[ty], bfr[tx], acc[ty][tx], 0, 0, 0);
        }
    }

    // epilogue (round-7 proven): C = sqrt(max(x2+y2-2S,0)); scalar bf16 stores; sum(C)
    float lsum = 0.0f;
    const int qr = lq * 4;
#pragma unroll
    for (int ty = 0; ty < 4; ++ty) {
        float x2r[4];
#pragma unroll
        for (int r = 0; r < 4; ++r)
            x2r[r] = x2[rb0 + wy * 64 + ty * 16 + qr + r];
#pragma unroll
        for (int tx = 0; tx < 4; ++tx) {
            int col = cb0 + wx * 64 + tx * 16 + lr;
            float y2c = y2[col];
#pragma unroll
            for (int r = 0; r < 4; ++r) {
                int row = rb0 + wy * 64 + ty * 16 + qr + r;
                float sq = x2r[r] + y2c - 2.0f * acc[ty][tx][r];
                float c = sqrtf(fmaxf(sq, 0.0f));
                lsum += c;
                Cb[(size_t)row * NN + col] = f2bf(c);
            }
        }
    }
    red[tid] = lsum;
    __syncthreads();
    for (int off = 128; off > 0; off >>= 1) {
        if (tid < off) red[tid] += red[tid + off];
        __syncthreads();
    }
    if (tid == 0) atomicAdd(sumC, red[0]);
}

// ---------------- ksum: ksumK[j] = sum_i exp(C_ij * nrs); uint4 loads, 512x128 blocks ----------------
__global__ __launch_bounds__(256) void sk_ksum_kernel(const unsigned short* __restrict__ Cb,
                                                      const float* __restrict__ sumC,
                                                      float* __restrict__ ksumK) {
    __shared__ float ks[4][516];
    const int t = threadIdx.x;
    const int g = t >> 6, ln = t & 63;
    const int c0 = blockIdx.x * 512 + ln * 8;
    const int r0 = blockIdx.y * 128 + g;
    const float mean = sumC[0] * (1.0f / ((float)NN * (float)NN));
    const float nrs = -1.0f / (mean * EPSV);
    float a[8] = {0, 0, 0, 0, 0, 0, 0, 0};
#pragma unroll
    for (int k = 0; k < 32; ++k) {
        int r = r0 + k * 4;
        uint4 cw = *(const uint4*)(Cb + (size_t)r * NN + c0);
        a[0] += __expf(bflo(cw.x) * nrs);
        a[1] += __expf(bfhi(cw.x) * nrs);
        a[2] += __expf(bflo(cw.y) * nrs);
        a[3] += __expf(bfhi(cw.y) * nrs);
        a[4] += __expf(bflo(cw.z) * nrs);
        a[5] += __expf(bfhi(cw.z) * nrs);
        a[6] += __expf(bflo(cw.w) * nrs);
        a[7] += __expf(bfhi(cw.w) * nrs);
    }
#pragma unroll
    for (int q = 0; q < 8; ++q) ks[g][ln * 8 + q] = a[q];
    __syncthreads();
    for (int c = t; c < 512; c += 256) {
        float s = ks[0][c] + ks[1][c] + ks[2][c] + ks[3][c];
        atomicAdd(&ksumK[blockIdx.x * 512 + c], s);
    }
}

// ---- fence-free hierarchical grid barrier (cross-block data uses sc0sc1 ops) ----
__device__ __forceinline__ void gridbar(unsigned* bar, unsigned target) {
    asm volatile("s_waitcnt vmcnt(0)" ::: "memory");
    __syncthreads();
    if (threadIdx.x == 0) {
        const int sg = blockIdx.x & 7;
        const unsigned bps = NB >> 3;
        unsigned p = __hip_atomic_fetch_add(&bar[sg * 32], 1u, __ATOMIC_RELAXED, __HIP_MEMORY_SCOPE_AGENT);
        if (p == target * bps - 1u) {
            unsigned q = __hip_atomic_fetch_add(&bar[256], 1u, __ATOMIC_RELAXED, __HIP_MEMORY_SCOPE_AGENT);
            if (q == target * 8u - 1u)
                __hip_atomic_store(&bar[288], target, __ATOMIC_RELAXED, __HIP_MEMORY_SCOPE_AGENT);
        }
        while (__hip_atomic_load(&bar[288], __ATOMIC_RELAXED, __HIP_MEMORY_SCOPE_AGENT) < target)
            __builtin_amdgcn_s_sleep(1);
    }
    __syncthreads();
}

// ---------------- Sinkhorn loop: it1 via ksum; Phase A fused with cost; bitwise fixed-point exit ----------------
__global__ __launch_bounds__(512, 4) void sk_coop_kernel(const unsigned short* __restrict__ Cb,
                                                         float* __restrict__ u,
                                                         float* __restrict__ v,
                                                         const float* __restrict__ ksumK,
                                                         const float* __restrict__ sumC,
                                                         unsigned* __restrict__ flags,
                                                         float* __restrict__ costpart,
                                                         unsigned* __restrict__ bar,
                                                         float* __restrict__ out) {
    __shared__ float vec[NN];          // 16 KB: v-cache (Phase A) / u-cache (fallback B)
    __shared__ float pu[RPB], pv[RPB];
    __shared__ float csum[RPB];
    __shared__ float ws8[8][8];
    const int t = threadIdx.x;         // 0..511
    const int bid = blockIdx.x;
    const int r8 = t >> 6;             // wave id 0..7 == row within block's chunk
    const int lane = t & 63;
    const float mean = sumC[0] * (1.0f / ((float)NN * (float)NN));
    const float nrs = -1.0f / (mean * EPSV);   // K = exp(C_raw * nrs)
    const float invMean = 1.0f / mean;
    unsigned bars = 0;

    // ---- it = 1: u1 = a/stab (uniform since v0 == 0); v1 = b/(u1*colsum(K) + stab) ----
    if (t < RPB) {
        float u1 = AVAL / (0.0f + STABV);
        pu[t] = u1;
        st_sys_f32(&u[bid * RPB + t], u1);
        float ks = ksumK[bid * RPB + t];       // prior dispatch: plain load is coherent
        float v1 = BVAL / (u1 * ks + STABV);
        pv[t] = v1;
        st_sys_f32(&v[bid * RPB + t], v1);
    }
    gridbar(bar, ++bars);

    for (int it = 2; it <= MAX_IT; ++it) {
        // ---- Phase A: u = a / (K v + stab), fused cost partial (rows of Cb) ----
        {
            float4 a = ld_sys_f32x4(v + t * 8);
            float4 b = ld_sys_f32x4(v + t * 8 + 4);
            *(float4*)&vec[t * 8] = a;
            *(float4*)&vec[t * 8 + 4] = b;
        }
        __syncthreads();
        const int i = bid * RPB + r8;
        const unsigned short* Crow = Cb + (size_t)i * NN;
        float acc = 0.0f, ts = 0.0f;
#pragma unroll
        for (int k = 0; k < 8; ++k) {
            int c0 = lane * 8 + k * 512;
            uint4 cw = *(const uint4*)(Crow + c0);
            float4 v0 = *(const float4*)&vec[c0];
            float4 v1 = *(const float4*)&vec[c0 + 4];
            float c, t1;
            c = bflo(cw.x); t1 = __expf(c * nrs) * v0.x; acc += t1; ts += t1 * c;
            c = bfhi(cw.x); t1 = __expf(c * nrs) * v0.y; acc += t1; ts += t1 * c;
            c = bflo(cw.y); t1 = __expf(c * nrs) * v0.z; acc += t1; ts += t1 * c;
            c = bfhi(cw.y); t1 = __expf(c * nrs) * v0.w; acc += t1; ts += t1 * c;
            c = bflo(cw.z); t1 = __expf(c * nrs) * v1.x; acc += t1; ts += t1 * c;
            c = bfhi(cw.z); t1 = __expf(c * nrs) * v1.y; acc += t1; ts += t1 * c;
            c = bflo(cw.w); t1 = __expf(c * nrs) * v1.z; acc += t1; ts += t1 * c;
            c = bfhi(cw.w); t1 = __expf(c * nrs) * v1.w; acc += t1; ts += t1 * c;
        }
#pragma unroll
        for (int off = 32; off > 0; off >>= 1) {
            acc += __shfl_down(acc, off, 64);
            ts += __shfl_down(ts, off, 64);
        }
        if (lane == 0) {
            float un = AVAL / (acc + STABV);
            if (un != pu[r8])
                __hip_atomic_store(&flags[it & 1], 1u, __ATOMIC_RELAXED, __HIP_MEMORY_SCOPE_AGENT);
            pu[r8] = un;
            st_sys_f32(&u[i], un);
            csum[r8] = un * ts * invMean;     // cost_i = u_i * sum_j K c v / mean
        }
        __syncthreads();
        if (t == 0) {
            float cp = 0.0f;
#pragma unroll
            for (int q = 0; q < RPB; ++q) cp += csum[q];
            st_sys_f32(&costpart[bid], cp);
        }
        if (bid == 0 && t == 0)
            __hip_atomic_store(&flags[(it + 1) & 1], 0u, __ATOMIC_RELAXED, __HIP_MEMORY_SCOPE_AGENT);
        gridbar(bar, ++bars);

        unsigned fl = __hip_atomic_load(&flags[it & 1], __ATOMIC_RELAXED, __HIP_MEMORY_SCOPE_AGENT);
        if (fl == 0u) break;   // u bitwise fixed -> deterministic recompute of v is fixed too

        // ---- Phase B (generic fallback): v = b/(K^T u + stab), col-stripe walk of Cb ----
        {
            float4 a = ld_sys_f32x4(u + t * 8);
            float4 b = ld_sys_f32x4(u + t * 8 + 4);
            *(float4*)&vec[t * 8] = a;
            *(float4*)&vec[t * 8 + 4] = b;
        }
        __syncthreads();
        const int j0 = bid * RPB;
        float a8[8] = {0, 0, 0, 0, 0, 0, 0, 0};
#pragma unroll
        for (int k = 0; k < 8; ++k) {
            int r = t + k * 512;
            uint4 cw = *(const uint4*)(Cb + (size_t)r * NN + j0);
            float ui = vec[r];
            a8[0] += __expf(bflo(cw.x) * nrs) * ui;
            a8[1] += __expf(bfhi(cw.x) * nrs) * ui;
            a8[2] += __expf(bflo(cw.y) * nrs) * ui;
            a8[3] += __expf(bfhi(cw.y) * nrs) * ui;
            a8[4] += __expf(bflo(cw.z) * nrs) * ui;
            a8[5] += __expf(bfhi(cw.z) * nrs) * ui;
            a8[6] += __expf(bflo(cw.w) * nrs) * ui;
            a8[7] += __expf(bfhi(cw.w) * nrs) * ui;
        }
#pragma unroll
        for (int off = 32; off > 0; off >>= 1)
#pragma unroll
            for (int q = 0; q < 8; ++q) a8[q] += __shfl_down(a8[q], off, 64);
        if (lane == 0)
#pragma unroll
            for (int q = 0; q < 8; ++q) ws8[r8][q] = a8[q];
        __syncthreads();
        if (t < RPB) {
            float s = 0.0f;
#pragma unroll
            for (int g = 0; g < 8; ++g) s += ws8[g][t];
            float vn = BVAL / (s + STABV);
            pv[t] = vn;
            st_sys_f32(&v[j0 + t], vn);
        }
        gridbar(bar, ++bars);
    }

    // ---- outputs: [cost, u(4096), v(4096)] ----
    if (t < RPB) {
        out[1 + bid * RPB + t] = pu[t];
        out[1 + NN + bid * RPB + t] = pv[t];
    }
    if (bid == 0) {
        __shared__ float cred[512];
        cred[t] = ld_sys_f32(&costpart[t]);
        __syncthreads();
        for (int off = 256; off > 0; off >>= 1) {
            if (t < off) cred[t] += cred[t + off];
            __syncthreads();
        }
        if (t == 0) out[0] = cred[0];
    }
}

extern "C" void kernel_launch(void* const* d_in, const int* in_sizes, int n_in,
                              void* d_out, int out_size, void* d_ws, size_t ws_size,
                              hipStream_t stream) {
    const float* x = (const float*)d_in[0];
    const float* y = (const float*)d_in[1];
    float* out = (float*)d_out;

    // ws layout
    unsigned short* Cb = (unsigned short*)d_ws;          // N*N bf16 = 32 MB
    unsigned short* xb = Cb + (size_t)NN * NN;           // N*D bf16
    unsigned short* yb = xb + (size_t)NN * DD;           // N*D bf16
    float* fbase = (float*)(yb + (size_t)NN * DD);
    float* x2    = fbase;                                // N
    float* y2    = x2 + NN;                              // N
    float* u     = y2 + NN;                              // N
    float* v     = u + NN;                               // N
    float* ksumK = v + NN;                               // N (colsums of K)
    float* costpart = ksumK + NN;                        // 512
    float* sumC  = costpart + 512;                       // 1
    unsigned* flags = (unsigned*)(sumC + 1);             // 2
    unsigned* bar   = flags + 2;                         // 384

    size_t need = ((size_t)NN * NN + 2 * (size_t)NN * DD) * 2
                + (5 * NN + 520) * sizeof(float) + 400 * sizeof(unsigned);
    if (ws_size < need) return;

    sk_conv_kernel<<<dim3(2 * NN / 4), dim3(256), 0, stream>>>(x, y, xb, yb, x2, y2, sumC, ksumK, flags, bar);
    sk_gemm_kernel<<<dim3(NN / 128, NN / 128), dim3(256), 0, stream>>>(xb, yb, x2, y2, Cb, sumC);
    sk_ksum_kernel<<<dim3(NN / 512, NN / 128), dim3(256), 0, stream>>>(Cb, sumC, ksumK);
    sk_coop_kernel<<<dim3(NB), dim3(512), 0, stream>>>(Cb, u, v, ksumK, sumC, flags, costpart, bar, out);
}